// Round 7
// baseline (125.202 us; speedup 1.0000x reference)
//
#include <hip/hip_runtime.h>
#include <hip/hip_bf16.h>

// Problem constants: B=16, D=256, T_enc=512, T_dec=2048
#define NB 16
#define ND 256
#define NK 512    // T_enc (contraction dim)
#define NT 2048   // T_dec (output cols)

// Geometry: round-0/6 base (best measured ~34-36us kernel): BM=BN=128, BK=32,
// 256 thr, 4 waves 2x2, each wave 64x64 via 4x4 of 16x16x32 bf16 MFMA.
// ONE structural change vs that base: staging via global_load_lds (async DMA,
// zero data-VGPRs -> no VGPR-forced load batching = one latency exposure/step)
// + 2-phase LDS double buffer (T3-minimum) so that exposure overlaps MFMA.
// LDS holds fp32 (DMA can't convert); cvt to bf16 happens in compute phase.
// Linear LDS (DMA requirement) + rule-#21 both-sides swizzle via pre-swizzled
// global source addresses.
// (R4/R5 container failures coincided with a sick-infra window — 585-929s npz
// pushes in R1/R3, healthy again in R6. Kernel re-audited: DMA dest linearity
// (m104), swizzle involutions both sides (rule #21), bounds, barrier uniformity
// all check out. Third and final attempt at this binary.)
#define BM 128
#define BN 128
#define BK 32
#define NSTEP (NK / BK)   // 16

typedef __attribute__((ext_vector_type(8))) short short8;   // 8 bf16 = 4 VGPRs
typedef __attribute__((ext_vector_type(4))) float f32x4;    // MFMA accumulator

union BF2U { __hip_bfloat162 h; unsigned int u; };
union S8U4 { short8 v; unsigned int u[4]; };

__device__ inline unsigned int pack2bf(float a, float b) {
    BF2U c; c.h = __float22bfloat162_rn(make_float2(a, b));
    return c.u;
}

// 16B-per-lane async global->LDS DMA. LDS dest = wave-uniform base + lane*16.
#define GLOAD_LDS(g, l) __builtin_amdgcn_global_load_lds(                     \
    (const __attribute__((address_space(1))) void*)(g),                       \
    (__attribute__((address_space(3))) void*)(l), 16, 0, 0)

__global__ __launch_bounds__(256, 2)
void bmm_bf16_mfma(const float* __restrict__ x, const float* __restrict__ path,
                   float* __restrict__ out) {
    const int n0 = blockIdx.x * BN;
    const int m0 = blockIdx.y * BM;
    const int b  = blockIdx.z;
    const int t    = threadIdx.x;
    const int lane = t & 63;
    const int wv   = t >> 6;          // wave id 0..3
    const int wr   = (wv >> 1) * 64;  // wave row offset in tile
    const int wc   = (wv & 1) * 64;   // wave col offset in tile
    const int q    = lane >> 4;       // quad 0..3
    const int lm   = lane & 15;

    // 64 KB: buf p at float offset p*8192. A tile (128x32 f32, 128B rows) at +0,
    // B tile (32x128 f32, 512B rows) at +4096. Linear layouts, data pre-swizzled
    // at the SOURCE so swizzled reads are conflict-free:
    //   A: 16B slot s of row r holds k-slot (s ^ (r&7))        [16-way -> spread]
    //   B: 16B slot s of k-row k holds col-slot (s ^ (((k>>3)&1)<<2)) [4->2-way]
    __shared__ float smem[2 * 8192];

    const float* xg = x    + ((size_t)b * ND + m0) * NK;   // A tile base
    const float* pg = path + (size_t)b * NK * NT + n0;     // B tile base

    // ---- Stage pointers: per-lane global src (pre-swizzled), wave-uniform LDS
    // chunk base. All loop-invariant; advance global ptrs by BK each stage.
    const float* gA[4]; const float* gB[4];
    float* lA[4];       float* lB[4];
#pragma unroll
    for (int i = 0; i < 4; ++i) {
        const int c  = wv * 4 + i;             // chunk 0..15, 1 KiB each
        // A chunk c = rows c*8..c*8+7; lane covers (row_off = l>>3, slot = l&7);
        // per-lane LDS landing offset = 4*l floats = linear (DMA constraint ok)
        const int ra = c * 8 + (lane >> 3);
        const int sa = (lane & 7) ^ (ra & 7);  // pre-swizzled source k-slot
        gA[i] = xg + (size_t)ra * NK + sa * 4;
        lA[i] = &smem[c * 256];
        // B chunk c = k-rows c*2, c*2+1; lane covers (k_off = l>>5, slot = l&31)
        const int kb = c * 2 + (lane >> 5);
        const int sb = (lane & 31) ^ (((kb >> 3) & 1) << 2);
        gB[i] = pg + (size_t)kb * NT + sb * 4;
        lB[i] = &smem[4096 + c * 256];
    }

    auto stage = [&](int bo) {                 // bo = buffer float offset (0/8192)
#pragma unroll
        for (int i = 0; i < 4; ++i) { GLOAD_LDS(gA[i], lA[i] + bo); gA[i] += BK; }
#pragma unroll
        for (int i = 0; i < 4; ++i) { GLOAD_LDS(gB[i], lB[i] + bo); gB[i] += (size_t)BK * NT; }
    };

    // ---- Compute-phase read offsets (float indices, loop-invariant).
    // A frag (row = wr+mt*16+lm, k = q*8..q*8+7): two b128 at slots (2q+h)^(lm&7).
    const int vA0 = (wr + lm) * 32 + (((2 * q + 0) ^ (lm & 7)) * 4);
    const int vA1 = (wr + lm) * 32 + (((2 * q + 1) ^ (lm & 7)) * 4);
    // B frag (col n = wc+nt*16+lm, k = q*8+j): source swizzle folds to nt^(q&1).
    int colB[4];
#pragma unroll
    for (int nt = 0; nt < 4; ++nt)
        colB[nt] = wc + ((nt ^ (q & 1)) * 16) + lm;

    f32x4 acc[4][4];
#pragma unroll
    for (int i = 0; i < 4; ++i)
#pragma unroll
        for (int j = 0; j < 4; ++j)
            acc[i][j] = (f32x4){0.f, 0.f, 0.f, 0.f};

    auto compute = [&](int bo) {
        short8 afr[4], bfr[4];
#pragma unroll
        for (int mt = 0; mt < 4; ++mt) {
            float4 x0 = *reinterpret_cast<const float4*>(&smem[bo + mt * 512 + vA0]);
            float4 x1 = *reinterpret_cast<const float4*>(&smem[bo + mt * 512 + vA1]);
            S8U4 s;
            s.u[0] = pack2bf(x0.x, x0.y);
            s.u[1] = pack2bf(x0.z, x0.w);
            s.u[2] = pack2bf(x1.x, x1.y);
            s.u[3] = pack2bf(x1.z, x1.w);
            afr[mt] = s.v;
        }
#pragma unroll
        for (int nt = 0; nt < 4; ++nt) {
            const float* bp = &smem[bo + 4096 + q * 1024 + colB[nt]];
            float f0 = bp[0 * 128], f1 = bp[1 * 128], f2 = bp[2 * 128], f3 = bp[3 * 128];
            float f4 = bp[4 * 128], f5 = bp[5 * 128], f6 = bp[6 * 128], f7 = bp[7 * 128];
            S8U4 s;
            s.u[0] = pack2bf(f0, f1);
            s.u[1] = pack2bf(f2, f3);
            s.u[2] = pack2bf(f4, f5);
            s.u[3] = pack2bf(f6, f7);
            bfr[nt] = s.v;
        }
        // Swapped operands (harness-verified R1-R3,R6): lane (q,lm) holds
        // C[m = lm][n = q*4 + r] -> f32x4 epilogue stores.
#pragma unroll
        for (int mt = 0; mt < 4; ++mt)
#pragma unroll
            for (int nt = 0; nt < 4; ++nt)
                acc[mt][nt] = __builtin_amdgcn_mfma_f32_16x16x32_bf16(
                    bfr[nt], afr[mt], acc[mt][nt], 0, 0, 0);
    };

    // ---- 2-phase pipeline (T3-minimum): stage(next) issued BEFORE compute(cur);
    // the __syncthreads() after compute drains vmcnt -> next buffer ready, and
    // the DMA latency hid under the ds_read+MFMA of the current buffer.
    stage(0);
    __syncthreads();
    for (int p = 0; p < NSTEP / 2; ++p) {
        stage(8192);                        // k-step 2p+1 -> buf1
        compute(0);                         // k-step 2p   <- buf0
        __syncthreads();
        if (p < NSTEP / 2 - 1) stage(0);    // k-step 2p+2 -> buf0
        compute(8192);                      // k-step 2p+1 <- buf1
        __syncthreads();
    }

    // ---- Epilogue: lane (q,lm) holds rows m=lm, cols q*4+0..3 (R1-R3,R6 verified)
    float* og = out + ((size_t)b * ND + m0 + wr) * NT + n0 + wc;
#pragma unroll
    for (int mt = 0; mt < 4; ++mt)
#pragma unroll
        for (int nt = 0; nt < 4; ++nt)
            *reinterpret_cast<f32x4*>(
                &og[(size_t)(mt * 16 + lm) * NT + nt * 16 + q * 4]) = acc[mt][nt];
}

extern "C" void kernel_launch(void* const* d_in, const int* in_sizes, int n_in,
                              void* d_out, int out_size, void* d_ws, size_t ws_size,
                              hipStream_t stream) {
    const float* x    = (const float*)d_in[0];   // [16, 256, 512]
    const float* path = (const float*)d_in[1];   // [16, 512, 2048]
    float* out        = (float*)d_out;           // [16, 256, 2048]
    dim3 grid(NT / BN, ND / BM, NB);             // (16, 2, 16) = 512 blocks
    dim3 block(256);
    bmm_bf16_mfma<<<grid, block, 0, stream>>>(x, path, out);
}